// Round 5
// baseline (107.017 us; speedup 1.0000x reference)
//
#include <hip/hip_runtime.h>

// Problem constants (from reference): B=2, L=8192, D=1024, f32 in/out.
#define BB 2
#define LL 8192
#define DD 1024
#define NC 64    // number of time chunks
#define TT 128   // chunk length = LL/NC (2^7)
#define NBLK ((DD / 256) * NC * BB)   // 4*64*2 = 512 blocks, 2/CU guaranteed

// ph = exp(-(pr^2+pi^2)) * exp(i*atan2(pi,pr))
__device__ __forceinline__ void compute_ph(float pr, float pi, float& phr, float& phi) {
    float r2 = fmaf(pr, pr, pi * pi);
    float mag = expf(-r2);
    float r = sqrtf(r2);
    if (r > 1e-30f) {
        float inv = mag / r;
        phr = pr * inv;
        phi = pi * inv;
    } else {
        phr = mag;  // atan2(0,0)=0 -> phase 1+0i
        phi = 0.0f;
    }
}

// Single-pass fused kernel with hand-rolled grid barrier.
// Co-residency: 512 blocks, __launch_bounds__(256,2) caps VGPR at 256 and
// guarantees 2 blocks/CU x 256 CUs = 512 resident -> barrier cannot deadlock.
__global__ __launch_bounds__(256, 2) void k_fused(
    const float* __restrict__ x,
    const float* __restrict__ pr, const float* __restrict__ pi,
    const float* __restrict__ qr, const float* __restrict__ qi,
    const float* __restrict__ lr, const float* __restrict__ li,
    float2* __restrict__ partial,
    unsigned int* __restrict__ bar,
    float* __restrict__ out)
{
    const int d = blockIdx.x * 256 + threadIdx.x;   // 0..1023
    const int j = blockIdx.y;                       // chunk
    const int b = blockIdx.z;                       // batch

    float phr, phi; compute_ph(pr[d], pi[d], phr, phi);
    const float qre = qr[d], qim = qi[d];

    const size_t base = ((size_t)b * LL + (size_t)j * TT) * DD + d;
    const float* xp = x + base;

    // ---- phase 1: x chunk -> VGPRs (static-indexed), zero-init partial ----
    float xv[TT];
    #pragma unroll
    for (int t = 0; t < TT; ++t) xv[t] = xp[(size_t)t * DD];

    {
        float sr = 0.f, si = 0.f;
        #pragma unroll
        for (int t = 0; t < TT; ++t) {
            float nr = fmaf(phr, sr, fmaf(-phi, si, qre * xv[t]));
            float ni = fmaf(phi, sr, fmaf(phr, si, qim * xv[t]));
            sr = nr; si = ni;
        }
        partial[((size_t)b * NC + j) * DD + d] = make_float2(sr, si);
    }

    // ---- grid barrier (device-scope; handles cross-XCD L2 non-coherence) ----
    __syncthreads();                      // drains this block's stores (vmcnt0)
    if (threadIdx.x == 0) {
        __threadfence();                  // release: write back dirty L2
        __hip_atomic_fetch_add(bar, 1u, __ATOMIC_ACQ_REL, __HIP_MEMORY_SCOPE_AGENT);
        while (__hip_atomic_load(bar, __ATOMIC_ACQUIRE, __HIP_MEMORY_SCOPE_AGENT) < NBLK) {
            __builtin_amdgcn_s_sleep(4);
        }
        __threadfence();                  // acquire: invalidate stale lines
    }
    __syncthreads();

    // ---- phase 2: a = ph^TT (7 squarings); fold partials 0..j-1 ----
    float ar = phr, ai = phi;
    #pragma unroll
    for (int k = 0; k < 7; ++k) {
        float nr = ar * ar - ai * ai;
        float ni = 2.f * ar * ai;
        ar = nr; ai = ni;
    }

    float Sr = lr[d], Si = li[d];
    const float2* pb = partial + (size_t)b * NC * DD + d;
    #pragma unroll 4
    for (int k = 0; k < j; ++k) {         // trip count uniform per block
        float2 P = pb[(size_t)k * DD];
        float nr = fmaf(ar, Sr, fmaf(-ai, Si, P.x));
        float ni = fmaf(ai, Sr, fmaf(ar, Si, P.y));
        Sr = nr; Si = ni;
    }

    // ---- phase 3: replay chunk from true start state, emit Re ----
    float* op = out + base;
    #pragma unroll
    for (int t = 0; t < TT; ++t) {
        float nr = fmaf(phr, Sr, fmaf(-phi, Si, qre * xv[t]));
        float ni = fmaf(phi, Sr, fmaf(phr, Si, qim * xv[t]));
        Sr = nr; Si = ni;
        op[(size_t)t * DD] = nr;
    }
}

extern "C" void kernel_launch(void* const* d_in, const int* in_sizes, int n_in,
                              void* d_out, int out_size, void* d_ws, size_t ws_size,
                              hipStream_t stream) {
    const float* x  = (const float*)d_in[0];
    const float* pr = (const float*)d_in[1];
    const float* pi = (const float*)d_in[2];
    const float* qr = (const float*)d_in[3];
    const float* qi = (const float*)d_in[4];
    const float* lr = (const float*)d_in[5];
    const float* li = (const float*)d_in[6];
    float* out = (float*)d_out;

    unsigned int* bar = (unsigned int*)d_ws;                  // 4 B counter
    float2* partial = (float2*)((char*)d_ws + 1024);          // BB*NC*DD*8 = 1 MB

    // reset barrier counter every call (graph-capture-safe async memset)
    hipMemsetAsync(d_ws, 0, 64, stream);

    dim3 grid(DD / 256, NC, BB);   // 4 x 64 x 2 = 512 blocks
    k_fused<<<grid, 256, 0, stream>>>(x, pr, pi, qr, qi, lr, li, partial, bar, out);
}

// Round 6
// 51.562 us; speedup vs baseline: 2.0755x; 2.0755x over previous
//
#include <hip/hip_runtime.h>

// Problem constants (from reference): B=2, L=8192, D=1024, f32 in/out.
#define BB 2
#define LL 8192
#define DD 1024
#define NC 128   // number of time chunks
#define TT 64    // chunk length = LL/NC (2^6)

// ph = exp(-(pr^2+pi^2)) * exp(i*atan2(pi,pr))
__device__ __forceinline__ void compute_ph(float pr, float pi, float& phr, float& phi) {
    float r2 = fmaf(pr, pr, pi * pi);
    float mag = expf(-r2);
    float r = sqrtf(r2);
    if (r > 1e-30f) {
        float inv = mag / r;
        phr = pr * inv;
        phi = pi * inv;
    } else {
        phr = mag;  // atan2(0,0)=0 -> phase 1+0i
        phi = 0.0f;
    }
}

// Pass 1: per-chunk end state with zero initial state. HBM-read-bound.
__global__ __launch_bounds__(256) void k_partial(
    const float* __restrict__ x,
    const float* __restrict__ pr, const float* __restrict__ pi,
    const float* __restrict__ qr, const float* __restrict__ qi,
    float2* __restrict__ partial)
{
    int d = blockIdx.x * 256 + threadIdx.x;
    int j = blockIdx.y;
    int b = blockIdx.z;
    float phr, phi; compute_ph(pr[d], pi[d], phr, phi);
    float qre = qr[d], qim = qi[d];
    const float* xp = x + ((size_t)b * LL + (size_t)j * TT) * DD + d;
    float sr = 0.f, si = 0.f;
    #pragma unroll 16
    for (int t = 0; t < TT; ++t) {
        float xv = xp[(size_t)t * DD];
        float nr = fmaf(phr, sr, fmaf(-phi, si, qre * xv));
        float ni = fmaf(phi, sr, fmaf(phr, si, qim * xv));
        sr = nr; si = ni;
    }
    partial[((size_t)b * NC + j) * DD + d] = make_float2(sr, si);
}

// Pass 2 (small, throughput-shaped): prefix-combine partials into per-chunk
// start states. One thread per (b,d); 128 address-independent loads pipelined
// 16-deep so L2/L3 latency is hidden. Fully coalesced (lane = d).
#define SCAN_DEPTH 16
__global__ __launch_bounds__(256) void k_scan(
    const float* __restrict__ pr, const float* __restrict__ pi,
    const float* __restrict__ lr, const float* __restrict__ li,
    const float2* __restrict__ partial,
    float2* __restrict__ Sarr)
{
    int idx = blockIdx.x * 256 + threadIdx.x;   // 0 .. BB*DD-1
    int d = idx & (DD - 1);
    int b = idx >> 10;                          // DD = 2^10

    float phr, phi; compute_ph(pr[d], pi[d], phr, phi);
    // a = ph^TT by repeated squaring (TT = 2^6)
    float ar = phr, ai = phi;
    #pragma unroll
    for (int k = 0; k < 6; ++k) {
        float nr = ar * ar - ai * ai;
        float ni = 2.f * ar * ai;
        ar = nr; ai = ni;
    }

    float Sr = lr[d], Si = li[d];
    const float2* pb = partial + (size_t)b * NC * DD + d;
    float2* sb = Sarr + (size_t)b * NC * DD + d;

    float2 buf[SCAN_DEPTH];
    #pragma unroll
    for (int u = 0; u < SCAN_DEPTH; ++u) buf[u] = pb[(size_t)u * DD];

    #pragma unroll
    for (int r = 0; r < NC / SCAN_DEPTH; ++r) {
        float2 nxt[SCAN_DEPTH];
        if (r < NC / SCAN_DEPTH - 1) {
            #pragma unroll
            for (int u = 0; u < SCAN_DEPTH; ++u)
                nxt[u] = pb[(size_t)((r + 1) * SCAN_DEPTH + u) * DD];
        }
        #pragma unroll
        for (int u = 0; u < SCAN_DEPTH; ++u) {
            int j = r * SCAN_DEPTH + u;
            sb[(size_t)j * DD] = make_float2(Sr, Si);
            float nr = fmaf(ar, Sr, fmaf(-ai, Si, buf[u].x));
            float ni = fmaf(ai, Sr, fmaf(ar, Si, buf[u].y));
            Sr = nr; Si = ni;
        }
        if (r < NC / SCAN_DEPTH - 1) {
            #pragma unroll
            for (int u = 0; u < SCAN_DEPTH; ++u) buf[u] = nxt[u];
        }
    }
}

// Pass 3: replay each chunk from its precomputed start state; emit Re(state).
// x is L3-resident after pass 1; stores are regular (L2 write-combining).
__global__ __launch_bounds__(256) void k_final(
    const float* __restrict__ x,
    const float* __restrict__ pr, const float* __restrict__ pi,
    const float* __restrict__ qr, const float* __restrict__ qi,
    const float2* __restrict__ Sarr,
    float* __restrict__ out)
{
    int d = blockIdx.x * 256 + threadIdx.x;
    int j = blockIdx.y;
    int b = blockIdx.z;
    float phr, phi; compute_ph(pr[d], pi[d], phr, phi);
    float qre = qr[d], qim = qi[d];

    float2 S = Sarr[((size_t)b * NC + j) * DD + d];
    float Sr = S.x, Si = S.y;

    const size_t base = ((size_t)b * LL + (size_t)j * TT) * DD + d;
    const float* xp = x + base;
    float* op = out + base;
    #pragma unroll 16
    for (int t = 0; t < TT; ++t) {
        float xv = xp[(size_t)t * DD];
        float nr = fmaf(phr, Sr, fmaf(-phi, Si, qre * xv));
        float ni = fmaf(phi, Sr, fmaf(phr, Si, qim * xv));
        Sr = nr; Si = ni;
        op[(size_t)t * DD] = nr;
    }
}

extern "C" void kernel_launch(void* const* d_in, const int* in_sizes, int n_in,
                              void* d_out, int out_size, void* d_ws, size_t ws_size,
                              hipStream_t stream) {
    const float* x  = (const float*)d_in[0];
    const float* pr = (const float*)d_in[1];
    const float* pi = (const float*)d_in[2];
    const float* qr = (const float*)d_in[3];
    const float* qi = (const float*)d_in[4];
    const float* lr = (const float*)d_in[5];
    const float* li = (const float*)d_in[6];
    float* out = (float*)d_out;

    float2* partial = (float2*)d_ws;                    // BB*NC*DD float2 = 2 MB
    float2* Sarr    = partial + (size_t)BB * NC * DD;   // 2 MB more

    dim3 grid(DD / 256, NC, BB);       // 4 x 128 x 2 = 1024 blocks
    k_partial<<<grid, 256, 0, stream>>>(x, pr, pi, qr, qi, partial);
    k_scan<<<(BB * DD) / 256, 256, 0, stream>>>(pr, pi, lr, li, partial, Sarr);
    k_final<<<grid, 256, 0, stream>>>(x, pr, pi, qr, qi, Sarr, out);
}